// Round 1
// baseline (3449.049 us; speedup 1.0000x reference)
//
#include <hip/hip_runtime.h>
#include <hip/hip_bf16.h>
#include <hip/hip_fp16.h>

// ---------------------------------------------------------------------------
// GRU forward, MI355X.
//   B=32, L=2048, D=256, H=256, 3H=768.
//   Phase 0: convert x,W_ih -> bf16 ; W_hh -> f16   (memory-bound passes)
//   Phase 1: xg = x @ W_ih^T + b_ih  via MFMA bf16 16x16x32, 128x128 tiles,
//            output f16 [B*L, 768]
//   Phase 2: persistent recurrence, 1 WG per batch (32 WGs), W_hh in VGPRs
//            as f16 pairs, v_dot2_f32_f16 matvec, h broadcast through LDS.
// ---------------------------------------------------------------------------

typedef _Float16 h2v __attribute__((ext_vector_type(2)));
typedef __attribute__((ext_vector_type(8))) short s8v;
typedef __attribute__((ext_vector_type(4))) float f4v;

// ---------------- converts ----------------

__device__ __forceinline__ unsigned short f2bf_rne(unsigned u) {
  return (unsigned short)((u + 0x7FFFu + ((u >> 16) & 1u)) >> 16);
}

__global__ void cvt_bf16_k(const float* __restrict__ s, unsigned short* __restrict__ d, int n8) {
  int i = blockIdx.x * blockDim.x + threadIdx.x;
  int st = gridDim.x * blockDim.x;
  const uint4* sp = (const uint4*)s;
  for (; i < n8; i += st) {
    uint4 a = sp[2 * i], b = sp[2 * i + 1];
    union { unsigned short us[8]; uint4 u; } o;
    o.us[0] = f2bf_rne(a.x); o.us[1] = f2bf_rne(a.y);
    o.us[2] = f2bf_rne(a.z); o.us[3] = f2bf_rne(a.w);
    o.us[4] = f2bf_rne(b.x); o.us[5] = f2bf_rne(b.y);
    o.us[6] = f2bf_rne(b.z); o.us[7] = f2bf_rne(b.w);
    ((uint4*)d)[i] = o.u;
  }
}

__global__ void cvt_f16_k(const float* __restrict__ s, __half* __restrict__ d, int n8) {
  int i = blockIdx.x * blockDim.x + threadIdx.x;
  int st = gridDim.x * blockDim.x;
  const float4* sp = (const float4*)s;
  for (; i < n8; i += st) {
    float4 a = sp[2 * i], b = sp[2 * i + 1];
    union { uint4 u; __half2 h[4]; } o;
    o.h[0] = __floats2half2_rn(a.x, a.y);
    o.h[1] = __floats2half2_rn(a.z, a.w);
    o.h[2] = __floats2half2_rn(b.x, b.y);
    o.h[3] = __floats2half2_rn(b.z, b.w);
    ((uint4*)d)[i] = o.u;
  }
}

// ---------------- phase 1: xg GEMM (bf16 MFMA) ----------------
// X: [M=65536, 256] bf16, W: [768, 256] bf16 (N x K, "B^T"), XG: [M, 768] f16
#define BT 48  // LDS row stride in elements (96 B: 16B-aligned rows, mild 4-way conflict)

__global__ __launch_bounds__(256) void gemm_xg(
    const unsigned short* __restrict__ X, const unsigned short* __restrict__ W,
    const float* __restrict__ bias, __half* __restrict__ XG) {
  __shared__ unsigned short As[128 * BT];
  __shared__ unsigned short Bs[128 * BT];
  const int tid = threadIdx.x;
  const int bm = blockIdx.x, bn = blockIdx.y;
  const int w = tid >> 6, l = tid & 63;
  const int wr = (w >> 1) * 64, wc = (w & 1) * 64;

  f4v acc[4][4];
#pragma unroll
  for (int a = 0; a < 4; ++a)
#pragma unroll
    for (int b = 0; b < 4; ++b) {
      acc[a][b][0] = 0.f; acc[a][b][1] = 0.f; acc[a][b][2] = 0.f; acc[a][b][3] = 0.f;
    }

  const long arow0 = (long)bm * 128;
  const int brow0 = bn * 128;

  for (int kb = 0; kb < 256; kb += 32) {
    // stage 128x32 bf16 tiles of A and B (each 8 KB), 16B chunks
#pragma unroll
    for (int cc = 0; cc < 2; ++cc) {
      int c = tid + cc * 256;
      int row = c >> 2, part = c & 3;
      uint4 av = *(const uint4*)(X + (arow0 + row) * 256 + kb + part * 8);
      *(uint4*)(&As[row * BT + part * 8]) = av;
      uint4 bv = *(const uint4*)(W + (long)(brow0 + row) * 256 + kb + part * 8);
      *(uint4*)(&Bs[row * BT + part * 8]) = bv;
    }
    __syncthreads();

    const int lr = l & 15, kg = (l >> 4) * 8;
    s8v af[4], bf[4];
#pragma unroll
    for (int mi = 0; mi < 4; ++mi) af[mi] = *(const s8v*)(&As[(wr + mi * 16 + lr) * BT + kg]);
#pragma unroll
    for (int ni = 0; ni < 4; ++ni) bf[ni] = *(const s8v*)(&Bs[(wc + ni * 16 + lr) * BT + kg]);
#pragma unroll
    for (int mi = 0; mi < 4; ++mi)
#pragma unroll
      for (int ni = 0; ni < 4; ++ni)
        acc[mi][ni] = __builtin_amdgcn_mfma_f32_16x16x32_bf16(af[mi], bf[ni], acc[mi][ni], 0, 0, 0);
    __syncthreads();
  }

  // epilogue: C/D layout col = lane&15, row = (lane>>4)*4 + r  [m89/m91]
  const int lr = l & 15, rg = (l >> 4) * 4;
#pragma unroll
  for (int mi = 0; mi < 4; ++mi)
#pragma unroll
    for (int ni = 0; ni < 4; ++ni) {
      int gcol = bn * 128 + wc + ni * 16 + lr;
      float bv = bias[gcol];
#pragma unroll
      for (int r = 0; r < 4; ++r) {
        long grow = arow0 + wr + mi * 16 + rg + r;
        XG[grow * 768 + gcol] = __float2half(acc[mi][ni][r] + bv);
      }
    }
}

// ---------------- phase 2: recurrence ----------------

__device__ __forceinline__ float fdot2f(h2v a, h2v b, float c) {
#if __has_builtin(__builtin_amdgcn_fdot2)
  return __builtin_amdgcn_fdot2(a, b, c, false);
#else
  return c + (float)a.x * (float)b.x + (float)a.y * (float)b.y;
#endif
}

__device__ __forceinline__ float rcp_fast(float x) {
#if __has_builtin(__builtin_amdgcn_rcpf)
  return __builtin_amdgcn_rcpf(x);
#else
  return 1.f / x;
#endif
}

// 32 blocks x 512 threads. threads 0..255: update rows (full K) + new-row k-half 0
//                          threads 256..511: reset rows (full K) + new-row k-half 1
__global__ __launch_bounds__(512, 2) void gru_rec(
    const __half* __restrict__ Whh, const __half* __restrict__ XG,
    float* __restrict__ Y) {
  const int b = blockIdx.x;
  const int tid = threadIdx.x;
  const int i = tid & 255;
  const int grp = tid >> 8;  // 0: update / 1: reset

  __shared__ __align__(16) __half hl[256];
  __shared__ float r_l[256];
  __shared__ float p1_l[256];

  union U4 { uint4 u; h2v h[4]; };

  // full row = row `tid` of W_hh (256 f16 = 128 v2f16 regs)
  h2v wfull[128];
  {
    const uint4* wr = (const uint4*)(Whh + (long)tid * 256);
#pragma unroll
    for (int j = 0; j < 32; ++j) {
      U4 q; q.u = wr[j];
      wfull[j * 4 + 0] = q.h[0]; wfull[j * 4 + 1] = q.h[1];
      wfull[j * 4 + 2] = q.h[2]; wfull[j * 4 + 3] = q.h[3];
    }
  }
  // half of row 512+i (new gate), k in [grp*128, grp*128+128)
  h2v whalf[64];
  {
    const uint4* wh = (const uint4*)(Whh + (long)(512 + i) * 256 + grp * 128);
#pragma unroll
    for (int j = 0; j < 16; ++j) {
      U4 q; q.u = wh[j];
      whalf[j * 4 + 0] = q.h[0]; whalf[j * 4 + 1] = q.h[1];
      whalf[j * 4 + 2] = q.h[2]; whalf[j * 4 + 3] = q.h[3];
    }
  }

  if (tid < 256) hl[i] = __float2half(0.f);
  float h_old = 0.f;
  __syncthreads();

  const long base = (long)b * 2048 * 768;
  const long ybase = (long)b * 2048 * 256;
  const int colA = grp ? (256 + i) : i;

  __half va_c = XG[base + colA];
  __half vb_c = __float2half(0.f);
  if (!grp) vb_c = XG[base + 512 + i];

  for (int t = 0; t < 2048; ++t) {
    // prefetch next step's xg (hidden under the dot phase)
    const long nx = base + (long)(t + 1 < 2048 ? t + 1 : 2047) * 768;
    __half va_n = XG[nx + colA];
    __half vb_n = vb_c;
    if (!grp) vb_n = XG[nx + 512 + i];

    float a0 = 0.f, a1 = 0.f, h0a = 0.f, h1a = 0.f;
#pragma unroll
    for (int c = 0; c < 32; ++c) {
      U4 hq;
      hq.u = *(const uint4*)(&hl[c * 8]);  // broadcast read, 8 h values
      a0 = fdot2f(wfull[c * 4 + 0], hq.h[0], a0);
      a1 = fdot2f(wfull[c * 4 + 1], hq.h[1], a1);
      a0 = fdot2f(wfull[c * 4 + 2], hq.h[2], a0);
      a1 = fdot2f(wfull[c * 4 + 3], hq.h[3], a1);
      if (c < 16) {
        if (!grp) {
          h0a = fdot2f(whalf[c * 4 + 0], hq.h[0], h0a);
          h1a = fdot2f(whalf[c * 4 + 1], hq.h[1], h1a);
          h0a = fdot2f(whalf[c * 4 + 2], hq.h[2], h0a);
          h1a = fdot2f(whalf[c * 4 + 3], hq.h[3], h1a);
        }
      } else {
        if (grp) {
          int cc = c - 16;
          h0a = fdot2f(whalf[cc * 4 + 0], hq.h[0], h0a);
          h1a = fdot2f(whalf[cc * 4 + 1], hq.h[1], h1a);
          h0a = fdot2f(whalf[cc * 4 + 2], hq.h[2], h0a);
          h1a = fdot2f(whalf[cc * 4 + 3], hq.h[3], h1a);
        }
      }
    }
    const float dF = a0 + a1;   // h_u (grp0) / h_r (grp1)
    const float dH = h0a + h1a; // partial h_n
    const float xv = __half2float(va_c);

    if (grp) {
      float r = rcp_fast(1.f + __expf(-(xv + dF)));
      r_l[i] = r;
      p1_l[i] = dH;
    }
    __syncthreads();
    if (!grp) {
      float z = rcp_fast(1.f + __expf(-(xv + dF)));
      float hn = dH + p1_l[i];
      float pre = __half2float(vb_c) + r_l[i] * hn;
      // tanh(pre) = 1 - 2/(1+e^{2 pre});  |pre| <= ~40 so e^{80} stays finite
      float e = __expf(2.f * pre);
      float n = 1.f - 2.f * rcp_fast(1.f + e);
      float hnew = z * h_old + (1.f - z) * n;
      Y[ybase + (long)t * 256 + i] = hnew;
      hl[i] = __float2half(hnew);
      h_old = hnew;
    }
    __syncthreads();
    va_c = va_n;
    vb_c = vb_n;
  }
}

// ---------------- launch ----------------

extern "C" void kernel_launch(void* const* d_in, const int* in_sizes, int n_in,
                              void* d_out, int out_size, void* d_ws, size_t ws_size,
                              hipStream_t stream) {
  const float* x   = (const float*)d_in[0];  // [32,2048,256]
  const float* Wih = (const float*)d_in[1];  // [768,256]
  const float* bih = (const float*)d_in[2];  // [768]
  const float* Whh = (const float*)d_in[3];  // [768,256]
  float* Y = (float*)d_out;                  // [32,2048,256]

  char* ws = (char*)d_ws;
  unsigned short* x16   = (unsigned short*)ws;                       // 33,554,432 B
  unsigned short* wih16 = (unsigned short*)(ws + 33554432);          //    393,216 B
  __half*         whh16 = (__half*)(ws + 33554432 + 393216);         //    393,216 B
  __half*         xg16  = (__half*)(ws + 33554432 + 2 * 393216);     // 100,663,296 B

  cvt_bf16_k<<<2048, 256, 0, stream>>>(x, x16, 16777216 / 8);
  cvt_bf16_k<<<96, 256, 0, stream>>>(Wih, wih16, 196608 / 8);
  cvt_f16_k<<<96, 256, 0, stream>>>(Whh, whh16, 196608 / 8);

  dim3 g(512, 6);
  gemm_xg<<<g, 256, 0, stream>>>(x16, wih16, bih, xg16);

  gru_rec<<<32, 512, 0, stream>>>(whh16, xg16, Y);
}